// Round 17
// baseline (415.405 us; speedup 1.0000x reference)
//
#include <hip/hip_runtime.h>

// GRU encoder, MI355X — R16 (resubmit after infra failure; never measured).
// Ablation round v2 (defeat top-5 masking): gru_abl_notrans (V1, 3x loop),
// gru_abl_nomfma (V2, 3x loop) get distinct names and ~3x duration so they DOMINATE
// the top-5 and are directly readable (/3). gru_main = exact R8 runs LAST (correct
// output). V1+V2 sum cross-checks R15's ~115-119us.

typedef __bf16 bf16x8 __attribute__((ext_vector_type(8)));
typedef float  f32x4  __attribute__((ext_vector_type(4)));
typedef int    int4v  __attribute__((ext_vector_type(4)));
typedef unsigned int uint2v __attribute__((ext_vector_type(2)));

#define NV   1000
#define EMB  64
#define HD   128
#define G3   384
#define SEQ  64
#define BB   16

#define SC_RZ (-1.4426950408889634f)
#define SC_N  ( 2.8853900817779268f)

__device__ __forceinline__ float bflo(unsigned int word) {
    return __builtin_bit_cast(float, word << 16);
}
__device__ __forceinline__ float bfhi(unsigned int word) {
    return __builtin_bit_cast(float, word & 0xffff0000u);
}

__global__ void g_table_kernel(const float* __restrict__ embed,
                               const float* __restrict__ W_ih,
                               const float* __restrict__ b_ih,
                               const float* __restrict__ b_hh,
                               unsigned short* __restrict__ Gpk)
{
    __shared__ float emb[EMB];
    const int v = blockIdx.x;
    const int g = threadIdx.x;
    if (g < EMB) emb[g] = embed[v * EMB + g];
    __syncthreads();
    const float* wr = W_ih + g * EMB;
    float s = b_ih[g] + (g < 2 * HD ? b_hh[g] : 0.f);
    #pragma unroll
    for (int e = 0; e < EMB; e += 4) {
        const float4 w4 = *(const float4*)(wr + e);
        s += w4.x * emb[e] + w4.y * emb[e + 1] + w4.z * emb[e + 2] + w4.w * emb[e + 3];
    }
    const int hid = g & 127, gate = g >> 7;
    s *= (gate < 2) ? SC_RZ : SC_N;
    const int w8 = hid >> 4, c16i = hid & 15;
    Gpk[((v * 8 + w8) * 16 + c16i) * 4 + gate] =
        __builtin_bit_cast(unsigned short, (__bf16)s);
}

// one GRU timestep; V=0 full, V=1 no-trans PW (bounded fake gates), V=2 no-MFMA.
#define GRU_STEP(P, T)                                                             \
  {                                                                                \
    int4v tk = {0, 0, 0, 0};                                                       \
    if ((T) < SEQ - 1) tk = *(const int4v*)&xl[((T) + 1) * BB + quad * 4];         \
    f32x4 acc[3];                                                                  \
    float xn_[4];                                                                  \
    _Pragma("unroll") for (int j = 0; j < 4; ++j) {                                \
      acc[0][j] = bflo(pf[j][0]);                                                  \
      acc[1][j] = bfhi(pf[j][0]);                                                  \
      acc[2][j] = bnw;                                                             \
      xn_[j]    = bflo(pf[j][1]);                                                  \
    }                                                                              \
    if constexpr (V != 2) {                                                        \
      _Pragma("unroll") for (int ks = 0; ks < 4; ++ks) {                           \
        const bf16x8 af = *(const bf16x8*)(hbase + (P) * 4096 + aoff[ks]);         \
        _Pragma("unroll") for (int gate = 0; gate < 3; ++gate)                     \
          acc[gate] = __builtin_amdgcn_mfma_f32_16x16x32_bf16(                     \
              af, wf[gate][ks], acc[gate], 0, 0, 0);                               \
      }                                                                            \
    }                                                                              \
    if ((T) < SEQ - 1) {                                                           \
      _Pragma("unroll") for (int j = 0; j < 4; ++j)                                \
        pf[j] = *(const uint2v*)(gbase + (unsigned)(tk[j] * 1024 + goff));         \
    }                                                                              \
    _Pragma("unroll") for (int j = 0; j < 4; ++j) {                                \
      float hn;                                                                    \
      if constexpr (V == 1) {                                                      \
        const float r  = __builtin_fmaf(acc[0][j], -0.125f, 0.5f);                 \
        const float zg = fminf(fmaxf(__builtin_fmaf(acc[1][j], -0.125f, 0.5f),     \
                                     0.f), 1.f);                                   \
        const float v_ = __builtin_fmaf(r, acc[2][j], xn_[j]);                     \
        const float n  = fminf(fmaxf(v_ * 0.25f, -1.f), 1.f);                      \
        hn = __builtin_fmaf(zg, hreg[j] - n, n);                                   \
      } else {                                                                     \
        const float r  = __builtin_amdgcn_rcpf(                                    \
            1.f + __builtin_amdgcn_exp2f(acc[0][j]));                              \
        const float zg = __builtin_amdgcn_rcpf(                                    \
            1.f + __builtin_amdgcn_exp2f(acc[1][j]));                              \
        const float v_ = __builtin_fmaf(r, acc[2][j], xn_[j]);                     \
        const float n  = __builtin_fmaf(-2.f,                                      \
            __builtin_amdgcn_rcpf(1.f + __builtin_amdgcn_exp2f(v_)), 1.f);         \
        hn = __builtin_fmaf(zg, hreg[j] - n, n);                                   \
      }                                                                            \
      hreg[j] = hn;                                                                \
      *(unsigned short*)(hbase + (1 - (P)) * 4096 + woff[j]) =                     \
          __builtin_bit_cast(unsigned short, (__bf16)hn);                          \
    }                                                                              \
    asm volatile("s_waitcnt lgkmcnt(0)" ::: "memory");                             \
    __builtin_amdgcn_s_barrier();                                                  \
    __builtin_amdgcn_sched_barrier(0);                                             \
  }

template<int V, int REPS>
__device__ __forceinline__ void gru_body(
    const int*   __restrict__ x,    const unsigned short* __restrict__ Gpk,
    const float* __restrict__ Whh,  const float* __restrict__ bhh,
    const float* __restrict__ Wout, const float* __restrict__ bout,
    float* __restrict__ out)
{
    __shared__ unsigned short hA[2 * BB * HD];
    __shared__ int xl[SEQ * BB];

    const int tid  = threadIdx.x;
    const int lane = tid & 63;
    const int w    = tid >> 6;
    const int c16  = lane & 15;
    const int quad = lane >> 4;
    const int br0  = blockIdx.x * BB;

    #pragma unroll
    for (int i = 0; i < 2; ++i) {
        const int idx = i * 512 + tid;
        const int r = idx >> 6;
        const int t = idx & 63;
        xl[t * BB + r] = x[(br0 + r) * SEQ + t];
    }
    {
        unsigned int* hA32 = (unsigned int*)hA;
        #pragma unroll
        for (int i = 0; i < 2; ++i)
            hA32[i * 512 + tid] = 0u;
    }

    bf16x8 wf[3][4];
    #pragma unroll
    for (int gate = 0; gate < 3; ++gate)
    #pragma unroll
    for (int ks = 0; ks < 4; ++ks) {
        const float sc = (gate < 2) ? SC_RZ : SC_N;
        const int col = gate * HD + w * 16 + c16;
        const float* p = Whh + col * HD + ks * 32 + quad * 4;
        const float4 a = *(const float4*)p;
        const float4 b = *(const float4*)(p + 16);
        bf16x8 f;
        f[0] = (__bf16)(sc * a.x); f[1] = (__bf16)(sc * a.y);
        f[2] = (__bf16)(sc * a.z); f[3] = (__bf16)(sc * a.w);
        f[4] = (__bf16)(sc * b.x); f[5] = (__bf16)(sc * b.y);
        f[6] = (__bf16)(sc * b.z); f[7] = (__bf16)(sc * b.w);
        wf[gate][ks] = f;
    }

    const float bnw = SC_N * bhh[2 * HD + w * 16 + c16];

    int aoff[4];
    #pragma unroll
    for (int ks = 0; ks < 4; ++ks)
        aoff[ks] = c16 * 256 + ((ks * 64 + quad * 16) ^ ((c16 & 7) << 4));
    int woff[4];
    {
        const int hid  = w * 16 + c16;
        const int sidx = ((hid >> 5) << 5) | (((hid & 15) >> 2) << 3)
                       | (((hid >> 4) & 1) << 2) | (hid & 3);
        #pragma unroll
        for (int j = 0; j < 4; ++j) {
            const int row = quad * 4 + j;
            woff[j] = row * 256 + ((sidx * 2) ^ ((row & 7) << 4));
        }
    }

    char* hbase = (char*)hA;
    const char* gbase = (const char*)Gpk;
    const int goff = w * 128 + c16 * 8;

    float hreg[4] = {0.f, 0.f, 0.f, 0.f};
    const f32x4 z4 = {0.f, 0.f, 0.f, 0.f};

    __syncthreads();

    uint2v pf[4];
    {
        const int4v tk0 = *(const int4v*)&xl[0 * BB + quad * 4];
        #pragma unroll
        for (int j = 0; j < 4; ++j)
            pf[j] = *(const uint2v*)(gbase + (unsigned)(tk0[j] * 1024 + goff));
    }

    for (int rep = 0; rep < REPS; ++rep) {
        for (int tt = 0; tt < SEQ; tt += 2) {
            GRU_STEP(0, tt)
            GRU_STEP(1, tt + 1)
        }
    }

    bf16x8 wo[4];
    #pragma unroll
    for (int ks = 0; ks < 4; ++ks) {
        const int col = w * 16 + c16;
        const float* p = Wout + col * HD + ks * 32 + quad * 4;
        const float4 a = *(const float4*)p;
        const float4 b = *(const float4*)(p + 16);
        bf16x8 f;
        f[0] = (__bf16)a.x; f[1] = (__bf16)a.y; f[2] = (__bf16)a.z; f[3] = (__bf16)a.w;
        f[4] = (__bf16)b.x; f[5] = (__bf16)b.y; f[6] = (__bf16)b.z; f[7] = (__bf16)b.w;
        wo[ks] = f;
    }
    const float bow = bout[w * 16 + c16];

    f32x4 oacc = z4;
    #pragma unroll
    for (int ks = 0; ks < 4; ++ks) {
        const bf16x8 af = *(const bf16x8*)(hbase + aoff[ks]);
        oacc = __builtin_amdgcn_mfma_f32_16x16x32_bf16(af, wo[ks], oacc, 0, 0, 0);
    }
    #pragma unroll
    for (int j = 0; j < 4; ++j) {
        const int row = br0 + quad * 4 + j;
        out[row * HD + w * 16 + c16] = oacc[j] + bow;
    }
}

__global__ __launch_bounds__(512, 4) void gru_abl_notrans(
    const int* __restrict__ x, const unsigned short* __restrict__ Gpk,
    const float* __restrict__ Whh, const float* __restrict__ bhh,
    const float* __restrict__ Wout, const float* __restrict__ bout,
    float* __restrict__ out)
{ gru_body<1, 3>(x, Gpk, Whh, bhh, Wout, bout, out); }

__global__ __launch_bounds__(512, 4) void gru_abl_nomfma(
    const int* __restrict__ x, const unsigned short* __restrict__ Gpk,
    const float* __restrict__ Whh, const float* __restrict__ bhh,
    const float* __restrict__ Wout, const float* __restrict__ bout,
    float* __restrict__ out)
{ gru_body<2, 3>(x, Gpk, Whh, bhh, Wout, bout, out); }

__global__ __launch_bounds__(512, 4) void gru_main(
    const int* __restrict__ x, const unsigned short* __restrict__ Gpk,
    const float* __restrict__ Whh, const float* __restrict__ bhh,
    const float* __restrict__ Wout, const float* __restrict__ bout,
    float* __restrict__ out)
{ gru_body<0, 1>(x, Gpk, Whh, bhh, Wout, bout, out); }

extern "C" void kernel_launch(void* const* d_in, const int* in_sizes, int n_in,
                              void* d_out, int out_size, void* d_ws, size_t ws_size,
                              hipStream_t stream) {
    const int*   x     = (const int*)  d_in[0];
    const float* embed = (const float*)d_in[1];
    const float* W_ih  = (const float*)d_in[2];
    const float* W_hh  = (const float*)d_in[3];
    const float* b_ih  = (const float*)d_in[4];
    const float* b_hh  = (const float*)d_in[5];
    const float* W_out = (const float*)d_in[6];
    const float* b_out = (const float*)d_in[7];
    float* outp = (float*)d_out;
    unsigned short* Gpk = (unsigned short*)d_ws;

    const int Bsz = in_sizes[0] / SEQ;             // 8192

    g_table_kernel<<<NV, G3, 0, stream>>>(embed, W_ih, b_ih, b_hh, Gpk);
    // Ablation: 3x-length variants (directly visible in top-5), then exact-R8 control
    // LAST so d_out is correct.
    gru_abl_notrans<<<Bsz / BB, 512, 0, stream>>>(x, Gpk, W_hh, b_hh, W_out, b_out, outp);
    gru_abl_nomfma <<<Bsz / BB, 512, 0, stream>>>(x, Gpk, W_hh, b_hh, W_out, b_out, outp);
    gru_main       <<<Bsz / BB, 512, 0, stream>>>(x, Gpk, W_hh, b_hh, W_out, b_out, outp);
}

// Round 18
// 97.969 us; speedup vs baseline: 4.2402x; 4.2402x over previous
//
#include <hip/hip_runtime.h>

// GRU encoder, MI355X — R18 = R8 + two ablation-guided cuts:
//  (1) T-cut: 5 trans/h instead of 6 — h' = (h*a2 + E_z*(E_n-1)) * rcp(a1*a2),
//      a1=1+E_z, a2=1+E_n (one rcp replaces z's and n's; exact algebra).
//  (2) setprio role-split: prio1 during ds_read+MFMA phase, prio0 during trans
//      phase — the 2 random-phase blocks/CU arbitrate in favor of the LDS/MFMA
//      critical path (T5/m191 mechanism).
// Ablation (R16): M(mfma+lds)=54us, T(trans)=30us, S=10us, serial. Base R8 94.4us.

typedef __bf16 bf16x8 __attribute__((ext_vector_type(8)));
typedef float  f32x4  __attribute__((ext_vector_type(4)));
typedef int    int4v  __attribute__((ext_vector_type(4)));
typedef unsigned int uint2v __attribute__((ext_vector_type(2)));

#define NV   1000
#define EMB  64
#define HD   128
#define G3   384
#define SEQ  64
#define BB   16   // batch rows per block

#define SC_RZ (-1.4426950408889634f)   // -log2(e): z=rcp(1+exp2(SC_RZ*s))
#define SC_N  ( 2.8853900817779268f)   // +2log2(e): tanh(v)=(E-1)/(E+1), E=exp2(SC_N*v/2*..)

__device__ __forceinline__ float bflo(unsigned int word) {
    return __builtin_bit_cast(float, word << 16);
}
__device__ __forceinline__ float bfhi(unsigned int word) {
    return __builtin_bit_cast(float, word & 0xffff0000u);
}

// Gpk[v][w8][c16][slot]: slots {0,1,2} = scaled {xr',xz',xn'} for hid=w8*16+c16.
__global__ void g_table_kernel(const float* __restrict__ embed,
                               const float* __restrict__ W_ih,
                               const float* __restrict__ b_ih,
                               const float* __restrict__ b_hh,
                               unsigned short* __restrict__ Gpk)
{
    __shared__ float emb[EMB];
    const int v = blockIdx.x;
    const int g = threadIdx.x;              // 0..383 = gate*128 + hid
    if (g < EMB) emb[g] = embed[v * EMB + g];
    __syncthreads();
    const float* wr = W_ih + g * EMB;
    float s = b_ih[g] + (g < 2 * HD ? b_hh[g] : 0.f);   // fold b_hh for r,z only
    #pragma unroll
    for (int e = 0; e < EMB; e += 4) {
        const float4 w4 = *(const float4*)(wr + e);
        s += w4.x * emb[e] + w4.y * emb[e + 1] + w4.z * emb[e + 2] + w4.w * emb[e + 3];
    }
    const int hid = g & 127, gate = g >> 7;
    s *= (gate < 2) ? SC_RZ : SC_N;                      // pre-scale for exp2-form gates
    const int w8 = hid >> 4, c16i = hid & 15;
    Gpk[((v * 8 + w8) * 16 + c16i) * 4 + gate] =
        __builtin_bit_cast(unsigned short, (__bf16)s);
}

// one GRU timestep. P = read-parity (compile-time), T = timestep.
// setprio(1): token read + C-init + ds_read + MFMA + xg prefetch (critical LDS/MFMA
// phase gets issue preference over the other block's trans burst); setprio(0): PW.
#define GRU_STEP(P, T)                                                             \
  {                                                                                \
    __builtin_amdgcn_s_setprio(1);                                                 \
    int4v tk = {0, 0, 0, 0};                                                       \
    if ((T) < SEQ - 1) tk = *(const int4v*)&xl[((T) + 1) * BB + quad * 4];         \
    f32x4 acc[3];                                                                  \
    float xn_[4];                                                                  \
    _Pragma("unroll") for (int j = 0; j < 4; ++j) {                                \
      acc[0][j] = bflo(pf[j][0]);    /* xr' (scaled) */                            \
      acc[1][j] = bfhi(pf[j][0]);    /* xz' (scaled) */                            \
      acc[2][j] = bnw;               /* bn' (scaled) */                            \
      xn_[j]    = bflo(pf[j][1]);    /* xn' (scaled) */                            \
    }                                                                              \
    _Pragma("unroll") for (int ks = 0; ks < 4; ++ks) {                             \
      const bf16x8 af = *(const bf16x8*)(hbase + (P) * 4096 + aoff[ks]);           \
      _Pragma("unroll") for (int gate = 0; gate < 3; ++gate)                       \
        acc[gate] = __builtin_amdgcn_mfma_f32_16x16x32_bf16(                       \
            af, wf[gate][ks], acc[gate], 0, 0, 0);                                 \
    }                                                                              \
    if ((T) < SEQ - 1) {                                                           \
      _Pragma("unroll") for (int j = 0; j < 4; ++j)                                \
        pf[j] = *(const uint2v*)(gbase + (unsigned)(tk[j] * 1024 + goff));         \
    }                                                                              \
    __builtin_amdgcn_s_setprio(0);                                                 \
    _Pragma("unroll") for (int j = 0; j < 4; ++j) {                                \
      const float Er = __builtin_amdgcn_exp2f(acc[0][j]);                          \
      const float r  = __builtin_amdgcn_rcpf(1.f + Er);                            \
      const float Ez = __builtin_amdgcn_exp2f(acc[1][j]);                          \
      const float a1 = 1.f + Ez;                                                   \
      const float v  = __builtin_fmaf(r, acc[2][j], xn_[j]);                       \
      const float En = __builtin_amdgcn_exp2f(v);                                  \
      const float a2 = 1.f + En;                                                   \
      const float m  = En - 1.f;                                                   \
      const float num = __builtin_fmaf(hreg[j], a2, Ez * m);                       \
      const float rd  = __builtin_amdgcn_rcpf(a1 * a2);                            \
      const float hn  = num * rd;                                                  \
      hreg[j] = hn;                                                                \
      *(unsigned short*)(hbase + (1 - (P)) * 4096 + woff[j]) =                     \
          __builtin_bit_cast(unsigned short, (__bf16)hn);                          \
    }                                                                              \
    asm volatile("s_waitcnt lgkmcnt(0)" ::: "memory");                             \
    __builtin_amdgcn_s_barrier();                                                  \
    __builtin_amdgcn_sched_barrier(0);                                             \
  }

__global__ __launch_bounds__(512, 4) void gru_kernel(
    const int*   __restrict__ x,    const unsigned short* __restrict__ Gpk,
    const float* __restrict__ Whh,  const float* __restrict__ bhh,
    const float* __restrict__ Wout, const float* __restrict__ bout,
    float* __restrict__ out)
{
    __shared__ unsigned short hA[2 * BB * HD];   // 2 x 4KB, frag-permuted + XOR swizzle
    __shared__ int xl[SEQ * BB];                 // 4KB, [t][row]

    const int tid  = threadIdx.x;
    const int lane = tid & 63;
    const int w    = tid >> 6;      // wave id 0..7 = 16-col team (per gate)
    const int c16  = lane & 15;
    const int quad = lane >> 4;
    const int br0  = blockIdx.x * BB;

    // ---- stage tokens transposed: xl[t*BB + r] = x[(br0+r)*SEQ + t]
    #pragma unroll
    for (int i = 0; i < 2; ++i) {
        const int idx = i * 512 + tid;     // 0..1023
        const int r = idx >> 6;            // 0..15
        const int t = idx & 63;
        xl[t * BB + r] = x[(br0 + r) * SEQ + t];
    }
    // ---- zero parity-0 h buffer (h0 = 0): 1024 dwords
    {
        unsigned int* hA32 = (unsigned int*)hA;
        #pragma unroll
        for (int i = 0; i < 2; ++i)
            hA32[i * 512 + tid] = 0u;
    }

    // ---- W_hh B-fragments: cols gate*128 + w*16 + c16 (gate-scaled)
    bf16x8 wf[3][4];
    #pragma unroll
    for (int gate = 0; gate < 3; ++gate)
    #pragma unroll
    for (int ks = 0; ks < 4; ++ks) {
        const float sc = (gate < 2) ? SC_RZ : SC_N;
        const int col = gate * HD + w * 16 + c16;
        const float* p = Whh + col * HD + ks * 32 + quad * 4;
        const float4 a = *(const float4*)p;
        const float4 b = *(const float4*)(p + 16);
        bf16x8 f;
        f[0] = (__bf16)(sc * a.x); f[1] = (__bf16)(sc * a.y);
        f[2] = (__bf16)(sc * a.z); f[3] = (__bf16)(sc * a.w);
        f[4] = (__bf16)(sc * b.x); f[5] = (__bf16)(sc * b.y);
        f[6] = (__bf16)(sc * b.z); f[7] = (__bf16)(sc * b.w);
        wf[gate][ks] = f;
    }

    const float bnw = SC_N * bhh[2 * HD + w * 16 + c16];   // scaled n-bias, this col

    // ---- hoisted per-lane-constant LDS offsets
    int aoff[4];
    #pragma unroll
    for (int ks = 0; ks < 4; ++ks)
        aoff[ks] = c16 * 256 + ((ks * 64 + quad * 16) ^ ((c16 & 7) << 4));
    int woff[4];
    {
        const int hid  = w * 16 + c16;
        const int sidx = ((hid >> 5) << 5) | (((hid & 15) >> 2) << 3)
                       | (((hid >> 4) & 1) << 2) | (hid & 3);
        #pragma unroll
        for (int j = 0; j < 4; ++j) {
            const int row = quad * 4 + j;
            woff[j] = row * 256 + ((sidx * 2) ^ ((row & 7) << 4));
        }
    }

    char* hbase = (char*)hA;
    const char* gbase = (const char*)Gpk;
    const int goff = w * 128 + c16 * 8;    // byte offset within a 1024B table row

    float hreg[4] = {0.f, 0.f, 0.f, 0.f};
    const f32x4 z4 = {0.f, 0.f, 0.f, 0.f};

    __syncthreads();   // xl + hA zeros visible (one-time full drain is fine)

    // ---- preload xg for t=0
    uint2v pf[4];
    {
        const int4v tk0 = *(const int4v*)&xl[0 * BB + quad * 4];
        #pragma unroll
        for (int j = 0; j < 4; ++j)
            pf[j] = *(const uint2v*)(gbase + (unsigned)(tk0[j] * 1024 + goff));
    }

    for (int tt = 0; tt < SEQ; tt += 2) {
        GRU_STEP(0, tt);       // reads parity 0, writes parity 1
        GRU_STEP(1, tt + 1);   // reads parity 1, writes parity 0
    }
    // after t=63 (odd): h_final in parity-0 buffer.

    // ---- epilogue: out = h_final @ W_out^T + b_out (wave's 16 cols)
    bf16x8 wo[4];
    #pragma unroll
    for (int ks = 0; ks < 4; ++ks) {
        const int col = w * 16 + c16;
        const float* p = Wout + col * HD + ks * 32 + quad * 4;
        const float4 a = *(const float4*)p;
        const float4 b = *(const float4*)(p + 16);
        bf16x8 f;
        f[0] = (__bf16)a.x; f[1] = (__bf16)a.y; f[2] = (__bf16)a.z; f[3] = (__bf16)a.w;
        f[4] = (__bf16)b.x; f[5] = (__bf16)b.y; f[6] = (__bf16)b.z; f[7] = (__bf16)b.w;
        wo[ks] = f;
    }
    const float bow = bout[w * 16 + c16];

    f32x4 oacc = z4;
    #pragma unroll
    for (int ks = 0; ks < 4; ++ks) {
        const bf16x8 af = *(const bf16x8*)(hbase + aoff[ks]);   // parity 0
        oacc = __builtin_amdgcn_mfma_f32_16x16x32_bf16(af, wo[ks], oacc, 0, 0, 0);
    }
    #pragma unroll
    for (int j = 0; j < 4; ++j) {
        const int row = br0 + quad * 4 + j;
        out[row * HD + w * 16 + c16] = oacc[j] + bow;
    }
}

extern "C" void kernel_launch(void* const* d_in, const int* in_sizes, int n_in,
                              void* d_out, int out_size, void* d_ws, size_t ws_size,
                              hipStream_t stream) {
    const int*   x     = (const int*)  d_in[0];
    const float* embed = (const float*)d_in[1];
    const float* W_ih  = (const float*)d_in[2];
    const float* W_hh  = (const float*)d_in[3];
    const float* b_ih  = (const float*)d_in[4];
    const float* b_hh  = (const float*)d_in[5];
    const float* W_out = (const float*)d_in[6];
    const float* b_out = (const float*)d_in[7];
    float* outp = (float*)d_out;
    unsigned short* Gpk = (unsigned short*)d_ws;   // 1000*8*16*4*2B = 1.024 MB

    const int Bsz = in_sizes[0] / SEQ;             // 8192

    g_table_kernel<<<NV, G3, 0, stream>>>(embed, W_ih, b_ih, b_hh, Gpk);
    gru_kernel<<<Bsz / BB, 512, 0, stream>>>(x, Gpk, W_hh, b_hh, W_out, b_out, outp);
}